// Round 1
// baseline (452.169 us; speedup 1.0000x reference)
//
#include <hip/hip_runtime.h>
#include <hip/hip_bf16.h>
#include <stdint.h>

typedef __bf16 bf16x8 __attribute__((ext_vector_type(8)));
typedef float f32x4 __attribute__((ext_vector_type(4)));
typedef unsigned short u16x8 __attribute__((ext_vector_type(8)));

#define AS1 __attribute__((address_space(1)))
#define AS3 __attribute__((address_space(3)))

__constant__ float c_nf4[16] = {
    -1.0f, -0.6961928009986877f, -0.5250730514526367f, -0.39491748809814453f,
    -0.28444138169288635f, -0.18477343022823334f, -0.09105003625154495f, 0.0f,
    0.07958029955625534f, 0.16093020141124725f, 0.24611230194568634f,
    0.33791524171829224f, 0.44070982933044434f, 0.5626170039176941f,
    0.7229568362236023f, 1.0f};

__device__ __forceinline__ unsigned short f2bf_rne(float f) {
  unsigned int u = __builtin_bit_cast(unsigned int, f);
  u += 0x7FFFu + ((u >> 16) & 1u);
  return (unsigned short)(u >> 16);
}

// W_eff[o][i] = nf4[q[o*IN+i]] * scale[(o*IN+i)/64] + 4.0 * sum_r B[o][r]*A[r][i]
__global__ __launch_bounds__(256) void k_dequant_fold(
    const int* __restrict__ q, const float* __restrict__ scale,
    const float* __restrict__ lA, const float* __restrict__ lB,
    unsigned short* __restrict__ w, int IN, int shIN, int R, long total8) {
  long idx = (long)blockIdx.x * 256 + threadIdx.x;
  if (idx >= total8) return;
  long e0 = idx * 8;
  int o = (int)(e0 >> shIN);
  int i0 = (int)(e0 & (IN - 1));
  float s = scale[e0 >> 6];  // groups of 64 along flat index; 8 | 64 so uniform here
  const int* qp = q + e0;
  int4 qa = *(const int4*)qp;
  int4 qb = *(const int4*)(qp + 4);
  float v[8];
  v[0] = c_nf4[qa.x & 15] * s; v[1] = c_nf4[qa.y & 15] * s;
  v[2] = c_nf4[qa.z & 15] * s; v[3] = c_nf4[qa.w & 15] * s;
  v[4] = c_nf4[qb.x & 15] * s; v[5] = c_nf4[qb.y & 15] * s;
  v[6] = c_nf4[qb.z & 15] * s; v[7] = c_nf4[qb.w & 15] * s;
  for (int r = 0; r < R; ++r) {
    float br = 4.0f * lB[o * R + r];
    const float* ap = lA + (long)r * IN + i0;
    float4 a0 = *(const float4*)ap;
    float4 a1 = *(const float4*)(ap + 4);
    v[0] += br * a0.x; v[1] += br * a0.y; v[2] += br * a0.z; v[3] += br * a0.w;
    v[4] += br * a1.x; v[5] += br * a1.y; v[6] += br * a1.z; v[7] += br * a1.w;
  }
  u16x8 pk;
#pragma unroll
  for (int j = 0; j < 8; ++j) pk[j] = f2bf_rne(v[j]);
  *(u16x8*)(w + e0) = pk;
}

__global__ __launch_bounds__(256) void k_cvt_bf16(
    const float* __restrict__ x, unsigned short* __restrict__ xb, long total8) {
  long idx = (long)blockIdx.x * 256 + threadIdx.x;
  if (idx >= total8) return;
  long e0 = idx * 8;
  float4 a0 = *(const float4*)(x + e0);
  float4 a1 = *(const float4*)(x + e0 + 4);
  u16x8 pk;
  pk[0] = f2bf_rne(a0.x); pk[1] = f2bf_rne(a0.y);
  pk[2] = f2bf_rne(a0.z); pk[3] = f2bf_rne(a0.w);
  pk[4] = f2bf_rne(a1.x); pk[5] = f2bf_rne(a1.y);
  pk[6] = f2bf_rne(a1.z); pk[7] = f2bf_rne(a1.w);
  *(u16x8*)(xb + e0) = pk;
}

// C[m][n] = sum_k Xb[m][k] * Wb[n][k] + bias[n]
// m97-structure: 128x128 tile, BK=32, 4 waves (2x2 of 64x64), 16x16x32 bf16 MFMA.
__global__ __launch_bounds__(256) void k_gemm_bt_bias(
    const unsigned short* __restrict__ Xb, const unsigned short* __restrict__ Wb,
    const float* __restrict__ bias, float* __restrict__ out,
    int M, int N, int K) {
  __shared__ unsigned short As[128][32];
  __shared__ unsigned short Bs[128][32];
  const int tid = threadIdx.x;
  const int wave = tid >> 6;
  const int lane = tid & 63;

  int bid = blockIdx.x;
  const int nwg = gridDim.x;
  if ((nwg & 7) == 0) {  // XCD-aware swizzle (bijective when 8 | nwg)
    const int cpx = nwg >> 3;
    bid = (bid & 7) * cpx + (bid >> 3);
  }
  const int nbn = N >> 7;
  const int m0 = (bid / nbn) << 7;
  const int n0 = (bid % nbn) << 7;

  const int wrow = (wave >> 1) << 6;  // wave row offset in tile
  const int wcol = (wave & 1) << 6;   // wave col offset in tile
  const int lrow = lane & 15;
  const int lk = (lane >> 4) << 3;

  f32x4 acc[4][4];
#pragma unroll
  for (int r = 0; r < 4; ++r)
#pragma unroll
    for (int c = 0; c < 4; ++c) acc[r][c] = (f32x4)0.0f;

  for (int k0 = 0; k0 < K; k0 += 32) {
    // ---- stage A,B tiles: 8192 B each, global_load_lds width=16 ----
#pragma unroll
    for (int j = 0; j < 2; ++j) {
      const int chunk = wave * 2 + j;         // 0..7, wave-uniform
      const int elem = chunk * 512 + lane * 8;
      const int row = elem >> 5;
      const int col = elem & 31;
      const unsigned short* srcA = Xb + (size_t)(m0 + row) * K + (k0 + col);
      const unsigned short* srcB = Wb + (size_t)(n0 + row) * K + (k0 + col);
      char* dstA = (char*)(&As[0][0]) + chunk * 1024;  // wave-uniform base; HW adds lane*16
      char* dstB = (char*)(&Bs[0][0]) + chunk * 1024;
      __builtin_amdgcn_global_load_lds((const AS1 void*)srcA, (AS3 void*)dstA, 16, 0, 0);
      __builtin_amdgcn_global_load_lds((const AS1 void*)srcB, (AS3 void*)dstB, 16, 0, 0);
    }
    __syncthreads();

    bf16x8 a[4], b[4];
#pragma unroll
    for (int r = 0; r < 4; ++r)
      a[r] = *(const bf16x8*)&As[wrow + r * 16 + lrow][lk];
#pragma unroll
    for (int c = 0; c < 4; ++c)
      b[c] = *(const bf16x8*)&Bs[wcol + c * 16 + lrow][lk];
#pragma unroll
    for (int r = 0; r < 4; ++r)
#pragma unroll
      for (int c = 0; c < 4; ++c)
        acc[r][c] = __builtin_amdgcn_mfma_f32_16x16x32_bf16(a[r], b[c], acc[r][c], 0, 0, 0);
    __syncthreads();
  }

  // ---- epilogue: C/D layout col=lane&15, row=(lane>>4)*4+reg ----
  const int cg = lane >> 4;
#pragma unroll
  for (int c = 0; c < 4; ++c) {
    const int col = n0 + wcol + c * 16 + (lane & 15);
    const float bv = bias[col];
#pragma unroll
    for (int r = 0; r < 4; ++r) {
      const int rbase = m0 + wrow + r * 16 + cg * 4;
#pragma unroll
      for (int j = 0; j < 4; ++j)
        out[(size_t)(rbase + j) * N + col] = acc[r][c][j] + bv;
    }
  }
}

extern "C" void kernel_launch(void* const* d_in, const int* in_sizes, int n_in,
                              void* d_out, int out_size, void* d_ws, size_t ws_size,
                              hipStream_t stream) {
  const float* x = (const float*)d_in[0];
  const int* qw = (const int*)d_in[1];
  const float* qs = (const float*)d_in[2];
  const float* bias = (const float*)d_in[3];
  const float* lA = (const float*)d_in[4];
  const float* lB = (const float*)d_in[5];
  float* out = (float*)d_out;

  const int OUT = in_sizes[3];
  const long qn = (long)in_sizes[1];
  const int IN = (int)(qn / OUT);
  const int R = in_sizes[5] / OUT;
  const long xn = (long)in_sizes[0];
  const int M = (int)(xn / IN);
  const int N = OUT, K = IN;

  unsigned short* Wb = (unsigned short*)d_ws;   // OUT*IN bf16
  unsigned short* Xb = Wb + qn;                 // M*IN bf16

  const int shIN = 31 - __builtin_clz((unsigned)IN);

  const long w8 = qn / 8;
  k_dequant_fold<<<(int)((w8 + 255) / 256), 256, 0, stream>>>(qw, qs, lA, lB, Wb, IN, shIN, R, w8);
  const long x8 = xn / 8;
  k_cvt_bf16<<<(int)((x8 + 255) / 256), 256, 0, stream>>>(x, Xb, x8);

  dim3 grid((M / 128) * (N / 128));
  k_gemm_bt_bias<<<grid, 256, 0, stream>>>(Xb, Wb, bias, out, M, N, K);
}

// Round 2
// 323.499 us; speedup vs baseline: 1.3977x; 1.3977x over previous
//
#include <hip/hip_runtime.h>
#include <hip/hip_bf16.h>
#include <stdint.h>

typedef __bf16 bf16x8 __attribute__((ext_vector_type(8)));
typedef float f32x4 __attribute__((ext_vector_type(4)));
typedef unsigned short u16x8 __attribute__((ext_vector_type(8)));

#define AS1 __attribute__((address_space(1)))
#define AS3 __attribute__((address_space(3)))

__constant__ float c_nf4[16] = {
    -1.0f, -0.6961928009986877f, -0.5250730514526367f, -0.39491748809814453f,
    -0.28444138169288635f, -0.18477343022823334f, -0.09105003625154495f, 0.0f,
    0.07958029955625534f, 0.16093020141124725f, 0.24611230194568634f,
    0.33791524171829224f, 0.44070982933044434f, 0.5626170039176941f,
    0.7229568362236023f, 1.0f};

__device__ __forceinline__ unsigned short f2bf_rne(float f) {
  unsigned int u = __builtin_bit_cast(unsigned int, f);
  u += 0x7FFFu + ((u >> 16) & 1u);
  return (unsigned short)(u >> 16);
}

__global__ __launch_bounds__(256) void k_dequant_fold(
    const int* __restrict__ q, const float* __restrict__ scale,
    const float* __restrict__ lA, const float* __restrict__ lB,
    unsigned short* __restrict__ w, int IN, int shIN, int R, long total8) {
  long idx = (long)blockIdx.x * 256 + threadIdx.x;
  if (idx >= total8) return;
  long e0 = idx * 8;
  int o = (int)(e0 >> shIN);
  int i0 = (int)(e0 & (IN - 1));
  float s = scale[e0 >> 6];
  const int* qp = q + e0;
  int4 qa = *(const int4*)qp;
  int4 qb = *(const int4*)(qp + 4);
  float v[8];
  v[0] = c_nf4[qa.x & 15] * s; v[1] = c_nf4[qa.y & 15] * s;
  v[2] = c_nf4[qa.z & 15] * s; v[3] = c_nf4[qa.w & 15] * s;
  v[4] = c_nf4[qb.x & 15] * s; v[5] = c_nf4[qb.y & 15] * s;
  v[6] = c_nf4[qb.z & 15] * s; v[7] = c_nf4[qb.w & 15] * s;
  for (int r = 0; r < R; ++r) {
    float br = 4.0f * lB[o * R + r];
    const float* ap = lA + (long)r * IN + i0;
    float4 a0 = *(const float4*)ap;
    float4 a1 = *(const float4*)(ap + 4);
    v[0] += br * a0.x; v[1] += br * a0.y; v[2] += br * a0.z; v[3] += br * a0.w;
    v[4] += br * a1.x; v[5] += br * a1.y; v[6] += br * a1.z; v[7] += br * a1.w;
  }
  u16x8 pk;
#pragma unroll
  for (int j = 0; j < 8; ++j) pk[j] = f2bf_rne(v[j]);
  *(u16x8*)(w + e0) = pk;
}

__global__ __launch_bounds__(256) void k_cvt_bf16(
    const float* __restrict__ x, unsigned short* __restrict__ xb, long total8) {
  long idx = (long)blockIdx.x * 256 + threadIdx.x;
  if (idx >= total8) return;
  long e0 = idx * 8;
  float4 a0 = *(const float4*)(x + e0);
  float4 a1 = *(const float4*)(x + e0 + 4);
  u16x8 pk;
  pk[0] = f2bf_rne(a0.x); pk[1] = f2bf_rne(a0.y);
  pk[2] = f2bf_rne(a0.z); pk[3] = f2bf_rne(a0.w);
  pk[4] = f2bf_rne(a1.x); pk[5] = f2bf_rne(a1.y);
  pk[6] = f2bf_rne(a1.z); pk[7] = f2bf_rne(a1.w);
  *(u16x8*)(xb + e0) = pk;
}

// ---------------------------------------------------------------------------
// 256x256 tile, BK=64, 8 waves (2M x 4N), 8-phase schedule (T2+T3+T4+T5).
// LDS: A[buf][half][128][64], B[buf][half][128][64] bf16, swizzled
// byte ^= ((row&7)<<4). Staging: tile t phases: p0:B0(t+1) p1:B1(t+1)
// p2:- p3:A0,A1(t+2)+vmcnt(4). Zero same-phase read/write overlap.
// ---------------------------------------------------------------------------
__global__ __launch_bounds__(512, 2) void k_gemm_256(
    const unsigned short* __restrict__ Xb, const unsigned short* __restrict__ Wb,
    const float* __restrict__ bias, float* __restrict__ out,
    int M, int N, int K) {
  __shared__ char smem[131072];
  const int tid = threadIdx.x;
  const int wid = tid >> 6;
  const int lane = tid & 63;
  const int wr = wid >> 2;                       // 0..1  (M half)
  const int wc = wid & 3;                        // 0..3  (N quarter)
  const int wcl = wc & 1;
  const int bhalfoff = 65536 + ((wc >> 1) << 14);
  const int l15 = lane & 15;
  const int l16 = lane >> 4;
  const int xorv = (l15 & 7) << 4;

  int bid = blockIdx.x;
  const int nwg = gridDim.x;
  if ((nwg & 7) == 0) { const int cpx = nwg >> 3; bid = (bid & 7) * cpx + (bid >> 3); }
  const int nbn = N >> 8;
  const int m0 = (bid / nbn) << 8;
  const int n0 = (bid % nbn) << 8;

  // per-lane pre-swizzled global source offsets for staging
  int rowj[2], gcj[2];
#pragma unroll
  for (int j = 0; j < 2; ++j) {
    const int lo = (wid * 2 + j) * 1024 + lane * 16;  // linear byte in 16KiB half
    const int row = lo >> 7;
    const int ls = lo ^ ((row & 7) << 4);             // inverse-swizzled source
    rowj[j] = row;
    gcj[j] = (ls & 127) >> 1;
  }
  const unsigned short* pA[2] = {
      Xb + (size_t)(m0 + rowj[0]) * K + gcj[0],
      Xb + (size_t)(m0 + rowj[1]) * K + gcj[1]};
  const unsigned short* pB[2] = {
      Wb + (size_t)(n0 + rowj[0]) * K + gcj[0],
      Wb + (size_t)(n0 + rowj[1]) * K + gcj[1]};
  const size_t halfstep = (size_t)128 * K;

#define STAGE_A(bufv, h, kt)                                                         \
  {                                                                                  \
    _Pragma("unroll") for (int j = 0; j < 2; ++j)                                    \
        __builtin_amdgcn_global_load_lds(                                            \
            (const AS1 void*)(pA[j] + (size_t)(h)*halfstep + (size_t)(kt) * 64),     \
            (AS3 void*)(smem + (bufv)*32768 + (h)*16384 + (wid * 2 + j) * 1024),     \
            16, 0, 0);                                                               \
  }
#define STAGE_B(bufv, h, kt)                                                         \
  {                                                                                  \
    _Pragma("unroll") for (int j = 0; j < 2; ++j)                                    \
        __builtin_amdgcn_global_load_lds(                                            \
            (const AS1 void*)(pB[j] + (size_t)(h)*halfstep + (size_t)(kt) * 64),     \
            (AS3 void*)(smem + 65536 + (bufv)*32768 + (h)*16384 + (wid*2+j)*1024),   \
            16, 0, 0);                                                               \
  }

  bf16x8 af[4][2], b0[2][2], b1[2][2];
  f32x4 acc[8][4];
#pragma unroll
  for (int i = 0; i < 8; ++i)
#pragma unroll
    for (int j = 0; j < 4; ++j) acc[i][j] = (f32x4)0.0f;

#define READ_A(Abase, mq)                                                            \
  _Pragma("unroll") for (int ii = 0; ii < 4; ++ii)                                   \
  _Pragma("unroll") for (int kk = 0; kk < 2; ++kk)                                   \
      af[ii][kk] = *(const bf16x8*)((Abase) + ((mq)*64 + ii*16 + l15) * 128 +        \
                                    (((kk)*64 + l16 * 16) ^ xorv));
#define READ_B(Bbase, q, arr)                                                        \
  _Pragma("unroll") for (int jj = 0; jj < 2; ++jj)                                   \
  _Pragma("unroll") for (int kk = 0; kk < 2; ++kk)                                   \
      arr[jj][kk] = *(const bf16x8*)((Bbase) + (wcl*64 + ((q)*2+jj)*16 + l15) * 128 +\
                                     (((kk)*64 + l16 * 16) ^ xorv));
#define MFMA_Q(mq, q, arr)                                                           \
  _Pragma("unroll") for (int ii = 0; ii < 4; ++ii)                                   \
  _Pragma("unroll") for (int jj = 0; jj < 2; ++jj)                                   \
  _Pragma("unroll") for (int kk = 0; kk < 2; ++kk)                                   \
      acc[(mq)*4+ii][(q)*2+jj] = __builtin_amdgcn_mfma_f32_16x16x32_bf16(            \
          af[ii][kk], arr[jj][kk], acc[(mq)*4+ii][(q)*2+jj], 0, 0, 0);

#define BAR __builtin_amdgcn_s_barrier()
#define LGK0                                               \
  {                                                        \
    asm volatile("s_waitcnt lgkmcnt(0)" ::: "memory");     \
    __builtin_amdgcn_sched_barrier(0);                     \
  }

  const int NT = K >> 6;

  // prologue: tile0 (8 loads) + A(1) (4 loads); drain tile0, keep A(1) in flight
  STAGE_A(0, 0, 0) STAGE_A(0, 1, 0) STAGE_B(0, 0, 0) STAGE_B(0, 1, 0)
  STAGE_A(1, 0, 1) STAGE_A(1, 1, 1)
  asm volatile("s_waitcnt vmcnt(4)" ::: "memory");
  BAR;

  for (int t = 0; t < NT; ++t) {
    const int buf = t & 1;
    int tB = t + 1; if (tB >= NT) tB -= NT;   // wrapped dummy stages keep vmcnt uniform
    int tA = t + 2; if (tA >= NT) tA -= NT;
    const char* Abase = smem + buf * 32768 + wr * 16384;
    const char* Bbase = smem + buf * 32768 + bhalfoff;

    // p0: quadrant (mq0,nq0)
    READ_A(Abase, 0)
    READ_B(Bbase, 0, b0)
    STAGE_B(buf ^ 1, 0, tB)
    BAR; LGK0;
    __builtin_amdgcn_s_setprio(1);
    MFMA_Q(0, 0, b0)
    __builtin_amdgcn_s_setprio(0);
    BAR;

    // p1: (mq0,nq1)
    READ_B(Bbase, 1, b1)
    STAGE_B(buf ^ 1, 1, tB)
    BAR; LGK0;
    __builtin_amdgcn_s_setprio(1);
    MFMA_Q(0, 1, b1)
    __builtin_amdgcn_s_setprio(0);
    BAR;

    // p2: (mq1,nq0)
    READ_A(Abase, 1)
    BAR; LGK0;
    __builtin_amdgcn_s_setprio(1);
    MFMA_Q(1, 0, b0)
    __builtin_amdgcn_s_setprio(0);
    BAR;

    // p3: (mq1,nq1) + stage A(t+2) + tile-boundary counted wait
    STAGE_A(buf, 0, tA) STAGE_A(buf, 1, tA)
    asm volatile("s_waitcnt vmcnt(4)" ::: "memory");
    BAR;
    __builtin_amdgcn_s_setprio(1);
    MFMA_Q(1, 1, b1)
    __builtin_amdgcn_s_setprio(0);
    BAR;
  }

  // epilogue: C/D layout col=lane&15, row=(lane>>4)*4+j
#pragma unroll
  for (int nf = 0; nf < 4; ++nf) {
    const int col = n0 + wc * 64 + nf * 16 + l15;
    const float bv = bias[col];
#pragma unroll
    for (int mi = 0; mi < 8; ++mi) {
      const int row = m0 + wr * 128 + mi * 16 + l16 * 4;
#pragma unroll
      for (int j = 0; j < 4; ++j)
        out[(size_t)(row + j) * N + col] = acc[mi][nf][j] + bv;
    }
  }
#undef STAGE_A
#undef STAGE_B
#undef READ_A
#undef READ_B
#undef MFMA_Q
#undef BAR
#undef LGK0
}

extern "C" void kernel_launch(void* const* d_in, const int* in_sizes, int n_in,
                              void* d_out, int out_size, void* d_ws, size_t ws_size,
                              hipStream_t stream) {
  const float* x = (const float*)d_in[0];
  const int* qw = (const int*)d_in[1];
  const float* qs = (const float*)d_in[2];
  const float* bias = (const float*)d_in[3];
  const float* lA = (const float*)d_in[4];
  const float* lB = (const float*)d_in[5];
  float* out = (float*)d_out;

  const int OUT = in_sizes[3];
  const long qn = (long)in_sizes[1];
  const int IN = (int)(qn / OUT);
  const int R = in_sizes[5] / OUT;
  const long xn = (long)in_sizes[0];
  const int M = (int)(xn / IN);
  const int N = OUT, K = IN;

  unsigned short* Wb = (unsigned short*)d_ws;   // OUT*IN bf16
  unsigned short* Xb = Wb + qn;                 // M*IN bf16

  const int shIN = 31 - __builtin_clz((unsigned)IN);

  const long w8 = qn / 8;
  k_dequant_fold<<<(int)((w8 + 255) / 256), 256, 0, stream>>>(qw, qs, lA, lB, Wb, IN, shIN, R, w8);
  const long x8 = xn / 8;
  k_cvt_bf16<<<(int)((x8 + 255) / 256), 256, 0, stream>>>(x, Xb, x8);

  dim3 grid((M / 256) * (N / 256));
  k_gemm_256<<<grid, 512, 0, stream>>>(Xb, Wb, bias, out, M, N, K);
}

// Round 3
// 322.861 us; speedup vs baseline: 1.4005x; 1.0020x over previous
//
#include <hip/hip_runtime.h>
#include <hip/hip_bf16.h>
#include <stdint.h>

typedef __bf16 bf16x8 __attribute__((ext_vector_type(8)));
typedef float f32x4 __attribute__((ext_vector_type(4)));
typedef unsigned short u16x8 __attribute__((ext_vector_type(8)));

#define AS1 __attribute__((address_space(1)))
#define AS3 __attribute__((address_space(3)))

__constant__ float c_nf4[16] = {
    -1.0f, -0.6961928009986877f, -0.5250730514526367f, -0.39491748809814453f,
    -0.28444138169288635f, -0.18477343022823334f, -0.09105003625154495f, 0.0f,
    0.07958029955625534f, 0.16093020141124725f, 0.24611230194568634f,
    0.33791524171829224f, 0.44070982933044434f, 0.5626170039176941f,
    0.7229568362236023f, 1.0f};

__device__ __forceinline__ unsigned short f2bf_rne(float f) {
  unsigned int u = __builtin_bit_cast(unsigned int, f);
  u += 0x7FFFu + ((u >> 16) & 1u);
  return (unsigned short)(u >> 16);
}

__global__ __launch_bounds__(256) void k_dequant_fold(
    const int* __restrict__ q, const float* __restrict__ scale,
    const float* __restrict__ lA, const float* __restrict__ lB,
    unsigned short* __restrict__ w, int IN, int shIN, int R, long total8) {
  long idx = (long)blockIdx.x * 256 + threadIdx.x;
  if (idx >= total8) return;
  long e0 = idx * 8;
  int o = (int)(e0 >> shIN);
  int i0 = (int)(e0 & (IN - 1));
  float s = scale[e0 >> 6];
  const int* qp = q + e0;
  int4 qa = *(const int4*)qp;
  int4 qb = *(const int4*)(qp + 4);
  float v[8];
  v[0] = c_nf4[qa.x & 15] * s; v[1] = c_nf4[qa.y & 15] * s;
  v[2] = c_nf4[qa.z & 15] * s; v[3] = c_nf4[qa.w & 15] * s;
  v[4] = c_nf4[qb.x & 15] * s; v[5] = c_nf4[qb.y & 15] * s;
  v[6] = c_nf4[qb.z & 15] * s; v[7] = c_nf4[qb.w & 15] * s;
  for (int r = 0; r < R; ++r) {
    float br = 4.0f * lB[o * R + r];
    const float* ap = lA + (long)r * IN + i0;
    float4 a0 = *(const float4*)ap;
    float4 a1 = *(const float4*)(ap + 4);
    v[0] += br * a0.x; v[1] += br * a0.y; v[2] += br * a0.z; v[3] += br * a0.w;
    v[4] += br * a1.x; v[5] += br * a1.y; v[6] += br * a1.z; v[7] += br * a1.w;
  }
  u16x8 pk;
#pragma unroll
  for (int j = 0; j < 8; ++j) pk[j] = f2bf_rne(v[j]);
  *(u16x8*)(w + e0) = pk;
}

__global__ __launch_bounds__(256) void k_cvt_bf16(
    const float* __restrict__ x, unsigned short* __restrict__ xb, long total8) {
  long idx = (long)blockIdx.x * 256 + threadIdx.x;
  if (idx >= total8) return;
  long e0 = idx * 8;
  float4 a0 = *(const float4*)(x + e0);
  float4 a1 = *(const float4*)(x + e0 + 4);
  u16x8 pk;
  pk[0] = f2bf_rne(a0.x); pk[1] = f2bf_rne(a0.y);
  pk[2] = f2bf_rne(a0.z); pk[3] = f2bf_rne(a0.w);
  pk[4] = f2bf_rne(a1.x); pk[5] = f2bf_rne(a1.y);
  pk[6] = f2bf_rne(a1.z); pk[7] = f2bf_rne(a1.w);
  *(u16x8*)(xb + e0) = pk;
}

// ---------------------------------------------------------------------------
// 256x256 tile, BK=64, 8 waves (2M x 4N), 4-phase/tile schedule (T2+T3+T4+T5)
// with uniform 2-tile staging lead: tile t stages ALL of tile t+2 into the
// CURRENT buffer after each region's last read (B after p1 -> staged p2;
// A after p2 -> staged p3). Single vmcnt(8)/tile drains tile t-1's stages,
// guaranteeing tile t+1's LDS data. Lead = 5-6 phases > HBM latency.
// ---------------------------------------------------------------------------
__global__ __launch_bounds__(512, 2) void k_gemm_256(
    const unsigned short* __restrict__ Xb, const unsigned short* __restrict__ Wb,
    const float* __restrict__ bias, float* __restrict__ out,
    int M, int N, int K) {
  __shared__ char smem[131072];
  const int tid = threadIdx.x;
  const int wid = tid >> 6;
  const int lane = tid & 63;
  const int wr = wid >> 2;                       // 0..1  (M half)
  const int wc = wid & 3;                        // 0..3  (N quarter)
  const int wcl = wc & 1;
  const int bhalfoff = 65536 + ((wc >> 1) << 14);
  const int l15 = lane & 15;
  const int l16 = lane >> 4;
  const int xorv = (l15 & 7) << 4;

  int bid = blockIdx.x;
  const int nwg = gridDim.x;
  if ((nwg & 7) == 0) { const int cpx = nwg >> 3; bid = (bid & 7) * cpx + (bid >> 3); }
  const int nbn = N >> 8;
  const int m0 = (bid / nbn) << 8;
  const int n0 = (bid % nbn) << 8;

  // per-lane pre-swizzled global source offsets for staging
  int rowj[2], gcj[2];
#pragma unroll
  for (int j = 0; j < 2; ++j) {
    const int lo = (wid * 2 + j) * 1024 + lane * 16;  // linear byte in 16KiB half
    const int row = lo >> 7;
    const int ls = lo ^ ((row & 7) << 4);             // inverse-swizzled source
    rowj[j] = row;
    gcj[j] = (ls & 127) >> 1;
  }
  const unsigned short* pA[2] = {
      Xb + (size_t)(m0 + rowj[0]) * K + gcj[0],
      Xb + (size_t)(m0 + rowj[1]) * K + gcj[1]};
  const unsigned short* pB[2] = {
      Wb + (size_t)(n0 + rowj[0]) * K + gcj[0],
      Wb + (size_t)(n0 + rowj[1]) * K + gcj[1]};
  const size_t halfstep = (size_t)128 * K;

#define STAGE_A(bufv, h, kt)                                                         \
  {                                                                                  \
    _Pragma("unroll") for (int j = 0; j < 2; ++j)                                    \
        __builtin_amdgcn_global_load_lds(                                            \
            (const AS1 void*)(pA[j] + (size_t)(h)*halfstep + (size_t)(kt) * 64),     \
            (AS3 void*)(smem + (bufv)*32768 + (h)*16384 + (wid * 2 + j) * 1024),     \
            16, 0, 0);                                                               \
  }
#define STAGE_B(bufv, h, kt)                                                         \
  {                                                                                  \
    _Pragma("unroll") for (int j = 0; j < 2; ++j)                                    \
        __builtin_amdgcn_global_load_lds(                                            \
            (const AS1 void*)(pB[j] + (size_t)(h)*halfstep + (size_t)(kt) * 64),     \
            (AS3 void*)(smem + 65536 + (bufv)*32768 + (h)*16384 + (wid*2+j)*1024),   \
            16, 0, 0);                                                               \
  }

  bf16x8 af[4][2], b0[2][2], b1[2][2];
  f32x4 acc[8][4];
#pragma unroll
  for (int i = 0; i < 8; ++i)
#pragma unroll
    for (int j = 0; j < 4; ++j) acc[i][j] = (f32x4)0.0f;

#define READ_A(Abase, mq)                                                            \
  _Pragma("unroll") for (int ii = 0; ii < 4; ++ii)                                   \
  _Pragma("unroll") for (int kk = 0; kk < 2; ++kk)                                   \
      af[ii][kk] = *(const bf16x8*)((Abase) + ((mq)*64 + ii*16 + l15) * 128 +        \
                                    (((kk)*64 + l16 * 16) ^ xorv));
#define READ_B(Bbase, q, arr)                                                        \
  _Pragma("unroll") for (int jj = 0; jj < 2; ++jj)                                   \
  _Pragma("unroll") for (int kk = 0; kk < 2; ++kk)                                   \
      arr[jj][kk] = *(const bf16x8*)((Bbase) + (wcl*64 + ((q)*2+jj)*16 + l15) * 128 +\
                                     (((kk)*64 + l16 * 16) ^ xorv));
#define MFMA_Q(mq, q, arr)                                                           \
  _Pragma("unroll") for (int ii = 0; ii < 4; ++ii)                                   \
  _Pragma("unroll") for (int jj = 0; jj < 2; ++jj)                                   \
  _Pragma("unroll") for (int kk = 0; kk < 2; ++kk)                                   \
      acc[(mq)*4+ii][(q)*2+jj] = __builtin_amdgcn_mfma_f32_16x16x32_bf16(            \
          af[ii][kk], arr[jj][kk], acc[(mq)*4+ii][(q)*2+jj], 0, 0, 0);

#define BAR __builtin_amdgcn_s_barrier()
#define LGK0                                               \
  {                                                        \
    asm volatile("s_waitcnt lgkmcnt(0)" ::: "memory");     \
    __builtin_amdgcn_sched_barrier(0);                     \
  }

  const int NT = K >> 6;

  // prologue: stage tile0->buf0 and tile1->buf1 (16 loads); drain tile0 (8 left)
  STAGE_A(0, 0, 0) STAGE_A(0, 1, 0) STAGE_B(0, 0, 0) STAGE_B(0, 1, 0)
  STAGE_A(1, 0, 1) STAGE_A(1, 1, 1) STAGE_B(1, 0, 1) STAGE_B(1, 1, 1)
  asm volatile("s_waitcnt vmcnt(8)" ::: "memory");
  BAR;

  for (int t = 0; t < NT; ++t) {
    const int buf = t & 1;
    int tS = t + 2; if (tS >= NT) tS -= NT;   // wrapped dummy stages keep vmcnt uniform
    const char* Abase = smem + buf * 32768 + wr * 16384;
    const char* Bbase = smem + buf * 32768 + bhalfoff;

    // p0: quadrant (mq0,nq0)
    READ_A(Abase, 0)
    READ_B(Bbase, 0, b0)
    BAR; LGK0;
    __builtin_amdgcn_s_setprio(1);
    MFMA_Q(0, 0, b0)
    __builtin_amdgcn_s_setprio(0);
    BAR;

    // p1: (mq0,nq1) — after this, all B regions of buf are fully consumed
    READ_B(Bbase, 1, b1)
    BAR; LGK0;
    __builtin_amdgcn_s_setprio(1);
    MFMA_Q(0, 1, b1)
    __builtin_amdgcn_s_setprio(0);
    BAR;

    // p2: (mq1,nq0) + stage B(t+2) into current buf (B free after p1)
    READ_A(Abase, 1)
    STAGE_B(buf, 0, tS) STAGE_B(buf, 1, tS)
    BAR; LGK0;
    __builtin_amdgcn_s_setprio(1);
    MFMA_Q(1, 0, b0)
    __builtin_amdgcn_s_setprio(0);
    BAR;

    // p3: (mq1,nq1) + stage A(t+2) (A free after p2) + counted tile wait
    STAGE_A(buf, 0, tS) STAGE_A(buf, 1, tS)
    asm volatile("s_waitcnt vmcnt(8)" ::: "memory");
    BAR;
    __builtin_amdgcn_s_setprio(1);
    MFMA_Q(1, 1, b1)
    __builtin_amdgcn_s_setprio(0);
    BAR;
  }

  // epilogue: C/D layout col=lane&15, row=(lane>>4)*4+j
#pragma unroll
  for (int nf = 0; nf < 4; ++nf) {
    const int col = n0 + wc * 64 + nf * 16 + l15;
    const float bv = bias[col];
#pragma unroll
    for (int mi = 0; mi < 8; ++mi) {
      const int row = m0 + wr * 128 + mi * 16 + l16 * 4;
#pragma unroll
      for (int j = 0; j < 4; ++j)
        out[(size_t)(row + j) * N + col] = acc[mi][nf][j] + bv;
    }
  }
#undef STAGE_A
#undef STAGE_B
#undef READ_A
#undef READ_B
#undef MFMA_Q
#undef BAR
#undef LGK0
}

extern "C" void kernel_launch(void* const* d_in, const int* in_sizes, int n_in,
                              void* d_out, int out_size, void* d_ws, size_t ws_size,
                              hipStream_t stream) {
  const float* x = (const float*)d_in[0];
  const int* qw = (const int*)d_in[1];
  const float* qs = (const float*)d_in[2];
  const float* bias = (const float*)d_in[3];
  const float* lA = (const float*)d_in[4];
  const float* lB = (const float*)d_in[5];
  float* out = (float*)d_out;

  const int OUT = in_sizes[3];
  const long qn = (long)in_sizes[1];
  const int IN = (int)(qn / OUT);
  const int R = in_sizes[5] / OUT;
  const long xn = (long)in_sizes[0];
  const int M = (int)(xn / IN);
  const int N = OUT, K = IN;

  unsigned short* Wb = (unsigned short*)d_ws;   // OUT*IN bf16
  unsigned short* Xb = Wb + qn;                 // M*IN bf16

  const int shIN = 31 - __builtin_clz((unsigned)IN);

  const long w8 = qn / 8;
  k_dequant_fold<<<(int)((w8 + 255) / 256), 256, 0, stream>>>(qw, qs, lA, lB, Wb, IN, shIN, R, w8);
  const long x8 = xn / 8;
  k_cvt_bf16<<<(int)((x8 + 255) / 256), 256, 0, stream>>>(x, Xb, x8);

  dim3 grid((M / 256) * (N / 256));
  k_gemm_256<<<grid, 512, 0, stream>>>(Xb, Wb, bias, out, M, N, K);
}

// Round 4
// 314.318 us; speedup vs baseline: 1.4386x; 1.0272x over previous
//
#include <hip/hip_runtime.h>
#include <hip/hip_bf16.h>
#include <stdint.h>

typedef __bf16 bf16x8 __attribute__((ext_vector_type(8)));
typedef float f32x4 __attribute__((ext_vector_type(4)));
typedef unsigned short u16x8 __attribute__((ext_vector_type(8)));

#define AS1 __attribute__((address_space(1)))
#define AS3 __attribute__((address_space(3)))

__constant__ float c_nf4[16] = {
    -1.0f, -0.6961928009986877f, -0.5250730514526367f, -0.39491748809814453f,
    -0.28444138169288635f, -0.18477343022823334f, -0.09105003625154495f, 0.0f,
    0.07958029955625534f, 0.16093020141124725f, 0.24611230194568634f,
    0.33791524171829224f, 0.44070982933044434f, 0.5626170039176941f,
    0.7229568362236023f, 1.0f};

__device__ __forceinline__ unsigned short f2bf_rne(float f) {
  unsigned int u = __builtin_bit_cast(unsigned int, f);
  u += 0x7FFFu + ((u >> 16) & 1u);
  return (unsigned short)(u >> 16);
}

__global__ __launch_bounds__(256) void k_dequant_fold(
    const int* __restrict__ q, const float* __restrict__ scale,
    const float* __restrict__ lA, const float* __restrict__ lB,
    unsigned short* __restrict__ w, int IN, int shIN, int R, long total8) {
  long idx = (long)blockIdx.x * 256 + threadIdx.x;
  if (idx >= total8) return;
  long e0 = idx * 8;
  int o = (int)(e0 >> shIN);
  int i0 = (int)(e0 & (IN - 1));
  float s = scale[e0 >> 6];
  const int* qp = q + e0;
  int4 qa = *(const int4*)qp;
  int4 qb = *(const int4*)(qp + 4);
  float v[8];
  v[0] = c_nf4[qa.x & 15] * s; v[1] = c_nf4[qa.y & 15] * s;
  v[2] = c_nf4[qa.z & 15] * s; v[3] = c_nf4[qa.w & 15] * s;
  v[4] = c_nf4[qb.x & 15] * s; v[5] = c_nf4[qb.y & 15] * s;
  v[6] = c_nf4[qb.z & 15] * s; v[7] = c_nf4[qb.w & 15] * s;
  for (int r = 0; r < R; ++r) {
    float br = 4.0f * lB[o * R + r];
    const float* ap = lA + (long)r * IN + i0;
    float4 a0 = *(const float4*)ap;
    float4 a1 = *(const float4*)(ap + 4);
    v[0] += br * a0.x; v[1] += br * a0.y; v[2] += br * a0.z; v[3] += br * a0.w;
    v[4] += br * a1.x; v[5] += br * a1.y; v[6] += br * a1.z; v[7] += br * a1.w;
  }
  u16x8 pk;
#pragma unroll
  for (int j = 0; j < 8; ++j) pk[j] = f2bf_rne(v[j]);
  *(u16x8*)(w + e0) = pk;
}

__global__ __launch_bounds__(256) void k_cvt_bf16(
    const float* __restrict__ x, unsigned short* __restrict__ xb, long total8) {
  long idx = (long)blockIdx.x * 256 + threadIdx.x;
  if (idx >= total8) return;
  long e0 = idx * 8;
  float4 a0 = *(const float4*)(x + e0);
  float4 a1 = *(const float4*)(x + e0 + 4);
  u16x8 pk;
  pk[0] = f2bf_rne(a0.x); pk[1] = f2bf_rne(a0.y);
  pk[2] = f2bf_rne(a0.z); pk[3] = f2bf_rne(a0.w);
  pk[4] = f2bf_rne(a1.x); pk[5] = f2bf_rne(a1.y);
  pk[6] = f2bf_rne(a1.z); pk[7] = f2bf_rne(a1.w);
  *(u16x8*)(xb + e0) = pk;
}

// ---------------------------------------------------------------------------
// 256x256 tile, BK=64, 8 waves (2M x 4N), 4 phases/tile, K-loop unrolled by 2
// so buf is a compile-time literal. All ds_read addresses = 1 of 4 lane-base
// VGPRs + literal offset (swizzle decomposed); stages use 8 running pointers
// (zero VALU steady-state). Reads balanced 8/4/8/4 via b0 pre-read at p3.
// ---------------------------------------------------------------------------
__global__ __launch_bounds__(512, 2) void k_gemm_256(
    const unsigned short* __restrict__ Xb, const unsigned short* __restrict__ Wb,
    const float* __restrict__ bias, float* __restrict__ out,
    int M, int N, int K) {
  __shared__ char smem[131072];
  const int tid = threadIdx.x;
  const int wid = tid >> 6;
  const int lane = tid & 63;
  const int wr = wid >> 2;
  const int wc = wid & 3;
  const int wcl = wc & 1;
  const int l15 = lane & 15;
  const int l16 = lane >> 4;

  // swizzle decomposition: (kk*64 + l16*16) ^ ((l15&7)<<4)
  //   = (kk*64 ^ kflip) + ((l16 ^ (l15&3))<<4)
  const int kflip = (l15 & 4) ? 64 : 0;
  const int lowx = ((l16 ^ (l15 & 3)) << 4);
  const int baseA0 = wr * 16384 + l15 * 128 + lowx + kflip;
  const int baseA1 = wr * 16384 + l15 * 128 + lowx + (64 ^ kflip);
  const int baseB0 = 65536 + (wc >> 1) * 16384 + wcl * 8192 + l15 * 128 + lowx + kflip;
  const int baseB1 = baseB0 + (64 ^ kflip) - kflip;

  int bid = blockIdx.x;
  const int nwg = gridDim.x;
  if ((nwg & 7) == 0) { const int cpx = nwg >> 3; bid = (bid & 7) * cpx + (bid >> 3); }
  const int nbn = N >> 8;
  const int m0 = (bid / nbn) << 8;
  const int n0 = (bid % nbn) << 8;

  // per-lane pre-swizzled global source offsets for staging
  int rowj[2], gcj[2];
#pragma unroll
  for (int j = 0; j < 2; ++j) {
    const int lo = (wid * 2 + j) * 1024 + lane * 16;
    const int row = lo >> 7;
    const int ls = lo ^ ((row & 7) << 4);
    rowj[j] = row;
    gcj[j] = (ls & 127) >> 1;
  }
  const size_t halfstep = (size_t)128 * K;
  const unsigned short* pSA0[2], * pSA1[2], * pSB0[2], * pSB1[2];
#pragma unroll
  for (int j = 0; j < 2; ++j) {
    pSA0[j] = Xb + (size_t)(m0 + rowj[j]) * K + gcj[j];
    pSA1[j] = pSA0[j] + halfstep;
    pSB0[j] = Wb + (size_t)(n0 + rowj[j]) * K + gcj[j];
    pSB1[j] = pSB0[j] + halfstep;
  }

#define ST_A(bufl, h, coff)                                                          \
  {                                                                                  \
    __builtin_amdgcn_global_load_lds((const AS1 void*)(pSA##h[0] + (coff)),          \
        (AS3 void*)(smem + (bufl) * 32768 + (h) * 16384 + wid * 2048), 16, 0, 0);    \
    __builtin_amdgcn_global_load_lds((const AS1 void*)(pSA##h[1] + (coff)),          \
        (AS3 void*)(smem + (bufl) * 32768 + (h) * 16384 + wid * 2048 + 1024),        \
        16, 0, 0);                                                                   \
  }
#define ST_B(bufl, h, coff)                                                          \
  {                                                                                  \
    __builtin_amdgcn_global_load_lds((const AS1 void*)(pSB##h[0] + (coff)),          \
        (AS3 void*)(smem + 65536 + (bufl) * 32768 + (h) * 16384 + wid * 2048),       \
        16, 0, 0);                                                                   \
    __builtin_amdgcn_global_load_lds((const AS1 void*)(pSB##h[1] + (coff)),          \
        (AS3 void*)(smem + 65536 + (bufl) * 32768 + (h) * 16384 + wid * 2048 + 1024),\
        16, 0, 0);                                                                   \
  }

  bf16x8 af[4][2], b0[2][2], b1[2][2];
  f32x4 acc[8][4];
#pragma unroll
  for (int i = 0; i < 8; ++i)
#pragma unroll
    for (int j = 0; j < 4; ++j) acc[i][j] = (f32x4)0.0f;

#define RD_A(bufl, mq)                                                               \
  _Pragma("unroll") for (int ii = 0; ii < 4; ++ii) {                                 \
    af[ii][0] = *(const bf16x8*)(smem + baseA0 +                                     \
                                 ((bufl) * 32768 + (mq) * 8192 + ii * 2048));        \
    af[ii][1] = *(const bf16x8*)(smem + baseA1 +                                     \
                                 ((bufl) * 32768 + (mq) * 8192 + ii * 2048));        \
  }
#define RD_B(bufl, q, arr)                                                           \
  _Pragma("unroll") for (int jj = 0; jj < 2; ++jj) {                                 \
    arr[jj][0] = *(const bf16x8*)(smem + baseB0 +                                    \
                                  ((bufl) * 32768 + (q) * 4096 + jj * 2048));        \
    arr[jj][1] = *(const bf16x8*)(smem + baseB1 +                                    \
                                  ((bufl) * 32768 + (q) * 4096 + jj * 2048));        \
  }
#define MFMA_Q(mq, q, arr)                                                           \
  _Pragma("unroll") for (int kk = 0; kk < 2; ++kk)                                   \
  _Pragma("unroll") for (int ii = 0; ii < 4; ++ii)                                   \
  _Pragma("unroll") for (int jj = 0; jj < 2; ++jj)                                   \
      acc[(mq)*4+ii][(q)*2+jj] = __builtin_amdgcn_mfma_f32_16x16x32_bf16(            \
          af[ii][kk], arr[jj][kk], acc[(mq)*4+ii][(q)*2+jj], 0, 0, 0);

#define BAR __builtin_amdgcn_s_barrier()
#define PRIO1 __builtin_amdgcn_s_setprio(1)
#define PRIO0 __builtin_amdgcn_s_setprio(0)
#define LGK0                                               \
  {                                                        \
    asm volatile("s_waitcnt lgkmcnt(0)" ::: "memory");     \
    __builtin_amdgcn_sched_barrier(0);                     \
  }
#define VM8 asm volatile("s_waitcnt vmcnt(8)" ::: "memory")

#define SUBTILE(bufl, SC)                                                            \
  /* p0 */                                                                           \
  RD_A(bufl, 0)                                                                      \
  BAR; LGK0; PRIO1; MFMA_Q(0, 0, b0) PRIO0; BAR;                                     \
  /* p1 */                                                                           \
  RD_B(bufl, 1, b1)                                                                  \
  BAR; LGK0; PRIO1; MFMA_Q(0, 1, b1) PRIO0; BAR;                                     \
  /* p2 */                                                                           \
  RD_A(bufl, 1)                                                                      \
  ST_B(bufl, 0, SC) ST_B(bufl, 1, SC)                                                \
  BAR; LGK0; PRIO1; MFMA_Q(1, 0, b0) PRIO0; BAR;                                     \
  /* p3 */                                                                           \
  ST_A(bufl, 0, SC) ST_A(bufl, 1, SC)                                                \
  VM8; BAR; PRIO1; MFMA_Q(1, 1, b1) PRIO0;                                           \
  RD_B((bufl) ^ 1, 0, b0)                                                            \
  BAR;

  const int NT = K >> 6;

  // prologue: stage tile0->buf0, tile1->buf1; drain tile0; pre-read b0(tile0)
  ST_A(0, 0, 0) ST_A(0, 1, 0) ST_B(0, 0, 0) ST_B(0, 1, 0)
  ST_A(1, 0, 64) ST_A(1, 1, 64) ST_B(1, 0, 64) ST_B(1, 1, 64)
  VM8;
  BAR;
  RD_B(0, 0, b0)
#pragma unroll
  for (int j = 0; j < 2; ++j) { pSA0[j] += 128; pSA1[j] += 128; pSB0[j] += 128; pSB1[j] += 128; }

  for (int t = 0; t < NT; t += 2) {
    SUBTILE(0, 0)
    SUBTILE(1, 64)
    if (t + 4 < NT) {
#pragma unroll
      for (int j = 0; j < 2; ++j) { pSA0[j] += 128; pSA1[j] += 128; pSB0[j] += 128; pSB1[j] += 128; }
    }
  }

  // epilogue: C/D layout col=lane&15, row=(lane>>4)*4+j
#pragma unroll
  for (int nf = 0; nf < 4; ++nf) {
    const int col = n0 + wc * 64 + nf * 16 + l15;
    const float bv = bias[col];
#pragma unroll
    for (int mi = 0; mi < 8; ++mi) {
      const int row = m0 + wr * 128 + mi * 16 + l16 * 4;
#pragma unroll
      for (int j = 0; j < 4; ++j)
        out[(size_t)(row + j) * N + col] = acc[mi][nf][j] + bv;
    }
  }
#undef ST_A
#undef ST_B
#undef RD_A
#undef RD_B
#undef MFMA_Q
#undef BAR
#undef PRIO1
#undef PRIO0
#undef LGK0
#undef VM8
#undef SUBTILE
}

extern "C" void kernel_launch(void* const* d_in, const int* in_sizes, int n_in,
                              void* d_out, int out_size, void* d_ws, size_t ws_size,
                              hipStream_t stream) {
  const float* x = (const float*)d_in[0];
  const int* qw = (const int*)d_in[1];
  const float* qs = (const float*)d_in[2];
  const float* bias = (const float*)d_in[3];
  const float* lA = (const float*)d_in[4];
  const float* lB = (const float*)d_in[5];
  float* out = (float*)d_out;

  const int OUT = in_sizes[3];
  const long qn = (long)in_sizes[1];
  const int IN = (int)(qn / OUT);
  const int R = in_sizes[5] / OUT;
  const long xn = (long)in_sizes[0];
  const int M = (int)(xn / IN);
  const int N = OUT, K = IN;

  unsigned short* Wb = (unsigned short*)d_ws;   // OUT*IN bf16
  unsigned short* Xb = Wb + qn;                 // M*IN bf16

  const int shIN = 31 - __builtin_clz((unsigned)IN);

  const long w8 = qn / 8;
  k_dequant_fold<<<(int)((w8 + 255) / 256), 256, 0, stream>>>(qw, qs, lA, lB, Wb, IN, shIN, R, w8);
  const long x8 = xn / 8;
  k_cvt_bf16<<<(int)((x8 + 255) / 256), 256, 0, stream>>>(x, Xb, x8);

  dim3 grid((M / 256) * (N / 256));
  k_gemm_256<<<grid, 512, 0, stream>>>(Xb, Wb, bias, out, M, N, K);
}